// Round 3
// baseline (311.353 us; speedup 1.0000x reference)
//
#include <hip/hip_runtime.h>

typedef __bf16 bf16;
typedef __attribute__((ext_vector_type(8))) __bf16 bf16x8;
typedef __attribute__((ext_vector_type(4))) __bf16 bf16x4;
typedef __attribute__((ext_vector_type(4))) float f32x4;

#define MFMA16(a, b, c) __builtin_amdgcn_mfma_f32_16x16x32_bf16(a, b, c, 0, 0, 0)

__device__ __forceinline__ int div7(int n) { return (n * 37) >> 8; }          // exact 0..63
__device__ __forceinline__ int relv(int n) { return n + 6 * div7(n); }        // 13*(n/7)+(n%7)

#define QSCALE 0.17677669529663687f   // 32^-0.5, folded into Q

// Streaming load of 8 consecutive fp32 (read-once data), round to bf16x8.
__device__ __forceinline__ bf16x8 LD8NT(const float* p) {
    f32x4 a = __builtin_nontemporal_load((const f32x4*)p);
    f32x4 b = __builtin_nontemporal_load((const f32x4*)(p + 4));
    bf16x8 r;
    r[0] = (bf16)a[0]; r[1] = (bf16)a[1]; r[2] = (bf16)a[2]; r[3] = (bf16)a[3];
    r[4] = (bf16)b[0]; r[5] = (bf16)b[1]; r[6] = (bf16)b[2]; r[7] = (bf16)b[3];
    return r;
}

// ---------------- prep: pack weights (bf16 MFMA B-frag order) + bake bias tables ----------
// ws layout:
//   bf16x8 frags [0,2304): Wq  [t=0..11][ks=0..2][lane]  (qkv_w)
//                [2304,3456): Wsk [t=0..5][ks=0..2][lane] (skip_w * QSCALE)
//                [3456,4608): Wpr [t=0..5][h=0..2][lane]  (proj_w, permuted quad layout)
//   f32 PB at byte 73728: [variant=4][h=3][key=64][query=64] logit offsets
//     = rel-pos bias + (-100 group mask) + (-20000 key-pad), variant = (wi==31)*2+(wj==31)
__global__ __launch_bounds__(256)
void prep(const float* __restrict__ qkv_w, const float* __restrict__ skip_w,
          const float* __restrict__ proj_w, const float* __restrict__ btab,
          bf16* __restrict__ ws)
{
    const int blk = blockIdx.x, tid = threadIdx.x;
    if (blk < 18) {
        const int j = blk * 256 + tid;
        bf16x8 v;
        if (j < 2304) {
            int t = j / 192, rem = j - t * 192;
            int ks = rem >> 6, lane = rem & 63, q = lane >> 4, l16 = lane & 15;
            const float* p = qkv_w + (16 * t + l16) * 96 + ks * 32 + q * 8;
            #pragma unroll
            for (int e = 0; e < 8; ++e) v[e] = (bf16)p[e];
        } else if (j < 3456) {
            int i = j - 2304;
            int t = i / 192, rem = i - t * 192;
            int ks = rem >> 6, lane = rem & 63, q = lane >> 4, l16 = lane & 15;
            const float* p = skip_w + (16 * t + l16) * 96 + ks * 32 + q * 8;
            #pragma unroll
            for (int e = 0; e < 8; ++e) v[e] = (bf16)(p[e] * QSCALE);
        } else {
            int i = j - 3456;
            int t = i / 192, rem = i - t * 192;
            int h = rem >> 6, lane = rem & 63, q = lane >> 4, l16 = lane & 15;
            const float* p = proj_w + (16 * t + l16) * 96 + 32 * h + 4 * q;
            #pragma unroll
            for (int r = 0; r < 4; ++r) { v[r] = (bf16)p[r]; v[4 + r] = (bf16)p[16 + r]; }
        }
        ((bf16x8*)ws)[j] = v;
    } else {
        const int idx = (blk - 18) * 256 + tid;          // 0..49151
        const int vh = idx >> 12;                        // variant*3 + h
        const int vr = vh / 3, h = vh - 3 * vr;
        const int ebit = vr >> 1, wbit = vr & 1;         // (wi==31), (wj==31)
        const int k = (idx >> 6) & 63, q = idx & 63;
        const int qc = (q < 49) ? q : 48;
        float val;
        if (k >= 49) {
            val = -20000.f;
        } else {
            val = btab[(relv(qc) + relv(48 - k)) * 3 + h];
            int rq = div7(qc), cq = qc - 7 * rq;
            int rk = div7(k),  ck = k - 7 * rk;
            int gq = (ebit ? (rq < 4 ? 3 : 6) : 0) + (wbit ? (cq < 4 ? 1 : 2) : 0);
            int gk = (ebit ? (rk < 4 ? 3 : 6) : 0) + (wbit ? (ck < 4 ? 1 : 2) : 0);
            if (gq != gk) val -= 100.f;
        }
        ((float*)(ws + 36864))[idx] = val;
    }
}

// ---------------- main: one block = one 7x7 window, 256 threads = 4 waves ----------------
__global__ __launch_bounds__(256, 4)
void swin_msa_kernel(const float* __restrict__ x_in,   const float* __restrict__ sx_in,
                     const bf16*  __restrict__ wpk,    const float* __restrict__ qkv_b,
                     const float* __restrict__ skip_b, const float* __restrict__ proj_b,
                     float* __restrict__ out)
{
    // LDS: Kb 64x104 (rows permuted by rho), Qb 64x104, VT 96x72 = 40448 B -> 4 blocks/CU
    __shared__ __align__(16) unsigned short smem[20224];
    bf16* Kb = (bf16*)smem;       // 64 x 104
    bf16* Qb = Kb + 6656;         // 64 x 104
    bf16* VT = Qb + 6656;         // 96 x 72  (V transposed: [channel][pixel])

    const int tid  = threadIdx.x;
    const int wv   = tid >> 6;
    const int lane = tid & 63;
    const int quad = lane >> 4;
    const int l16  = lane & 15;

    const int win  = blockIdx.x;
    const int bimg = win >> 10;
    const int wrem = win & 1023;
    const int wi   = wrem >> 5;
    const int wj   = wrem & 31;

    const f32x4 zero4 = {0.f, 0.f, 0.f, 0.f};
    const int koff = quad * 8;

    // packed weight fragment streams for THIS lane (wave reads dense 1 KB per instr)
    const bf16x8* WQ = (const bf16x8*)wpk + lane;          // + (t*3+ks)*64
    const bf16x8* WS = (const bf16x8*)wpk + 2304 + lane;   // + (t*3+ks)*64
    const bf16x8* WP = (const bf16x8*)wpk + 3456 + lane;   // + (t*3+h)*64

    // my pixel: p = 16*wv + l16
    const int pq  = 16 * wv + l16;
    const int pqc = (pq < 49) ? pq : 48;
    int pr = div7(pqc), pc = pqc - 7 * pr;
    int h0 = wi * 7 + pr + 3; if (h0 >= 224) h0 -= 224;     // roll(-3) gather
    int w0 = wj * 7 + pc + 3; if (w0 >= 224) w0 -= 224;
    const int gbase = ((bimg * 224 + h0) * 224 + w0) * 96;

    // baked logit-offset table for this window variant / this lane's (quad, query)
    const int variant = ((wi == 31) ? 2 : 0) + ((wj == 31) ? 1 : 0);
    const float* PBl = (const float*)(wpk + 36864) + (variant * 3) * 4096 + (8 * quad) * 64 + pq;

    // ---- stage B1: KV = X @ qkv_w^T + b (M-split: wave owns its 16 pixel rows) ----
    {
        f32x4 acc[12];
        #pragma unroll
        for (int t = 0; t < 12; ++t) acc[t] = zero4;
        #pragma unroll
        for (int ks = 0; ks < 3; ++ks) {
            bf16x8 a = LD8NT(x_in + gbase + ks * 32 + koff);
            #pragma unroll
            for (int t = 0; t < 12; ++t)
                acc[t] = MFMA16(a, WQ[(t * 3 + ks) * 64], acc[t]);
        }
        // K rows at rho(key): key=16wv+4quad+r -> row 32(wv>>1)+16(quad&1)+8(wv&1)+4(quad>>1)+r
        const int rho = 32 * (wv >> 1) + 16 * (quad & 1) + 8 * (wv & 1) + 4 * (quad >> 1);
        #pragma unroll
        for (int t = 0; t < 6; ++t) {
            const float bias = qkv_b[16 * t + l16];
            #pragma unroll
            for (int r = 0; r < 4; ++r)
                Kb[(rho + r) * 104 + 16 * t + l16] = (bf16)(acc[t][r] + bias);
        }
        const int pout = 16 * wv + 4 * quad;
        #pragma unroll
        for (int t = 6; t < 12; ++t) {
            const float bias = qkv_b[16 * t + l16];
            const int ch = 16 * (t - 6) + l16;
            bf16x4 vv;
            #pragma unroll
            for (int r = 0; r < 4; ++r) vv[r] = (bf16)(acc[t][r] + bias);
            *(bf16x4*)(VT + ch * 72 + pout) = vv;
        }
    }
    // ---- stage B2: Q = SX @ (skip_w*scale)^T + b*scale ----
    {
        f32x4 qa[6];
        #pragma unroll
        for (int t = 0; t < 6; ++t) qa[t] = zero4;
        #pragma unroll
        for (int ks = 0; ks < 3; ++ks) {
            bf16x8 a = LD8NT(sx_in + gbase + ks * 32 + koff);
            #pragma unroll
            for (int t = 0; t < 6; ++t)
                qa[t] = MFMA16(a, WS[(t * 3 + ks) * 64], qa[t]);
        }
        const int row = 16 * wv + 4 * quad;
        #pragma unroll
        for (int t = 0; t < 6; ++t) {
            const float bias = skip_b[16 * t + l16] * QSCALE;
            #pragma unroll
            for (int r = 0; r < 4; ++r)
                Qb[(row + r) * 104 + 16 * t + l16] = (bf16)(qa[t][r] + bias);
        }
    }
    __syncthreads();   // the only barrier: Kb/Qb/VT visible, read-only hereafter

    // ---- stage C: attention + proj, fully in registers ----
    // slot (nt,r) at this lane holds key = 8*quad + 32*(nt>>1) + 4*(nt&1) + r
    f32x4 dacc[6];
    #pragma unroll
    for (int t = 0; t < 6; ++t) dacc[t] = zero4;

    #pragma unroll
    for (int h = 0; h < 3; ++h) {
        const float* PBh = PBl + h * 4096;
        // S^T = K_perm . Q^T : rows = permuted keys, cols = queries (l16)
        const bf16x8 bq = *(const bf16x8*)(Qb + (16 * wv + l16) * 104 + 32 * h + koff);
        f32x4 s[4];
        #pragma unroll
        for (int nt = 0; nt < 4; ++nt) {
            bf16x8 ak = *(const bf16x8*)(Kb + (16 * nt + l16) * 104 + 32 * h + koff);
            s[nt] = MFMA16(ak, bq, zero4);
        }
        // logits = S + baked(bias, mask, pad); offsets are compile-time imm from PBh
        float v[16];
        #pragma unroll
        for (int nt = 0; nt < 4; ++nt)
            #pragma unroll
            for (int r = 0; r < 4; ++r) {
                const int c = (nt >> 1) * 32 + (nt & 1) * 4 + r;   // key - 8*quad
                v[nt * 4 + r] = s[nt][r] + PBh[c * 64];
            }
        // softmax over 64 keys: 16 in-lane + 2 cross-quad shuffles
        float m01 = fmaxf(fmaxf(v[0], v[1]), fmaxf(v[2], v[3]));
        float m23 = fmaxf(fmaxf(v[4], v[5]), fmaxf(v[6], v[7]));
        float m45 = fmaxf(fmaxf(v[8], v[9]), fmaxf(v[10], v[11]));
        float m67 = fmaxf(fmaxf(v[12], v[13]), fmaxf(v[14], v[15]));
        float mx = fmaxf(fmaxf(m01, m23), fmaxf(m45, m67));
        mx = fmaxf(mx, __shfl_xor(mx, 16));
        mx = fmaxf(mx, __shfl_xor(mx, 32));
        #pragma unroll
        for (int i = 0; i < 16; ++i) v[i] = __expf(v[i] - mx);
        float s01 = (v[0] + v[1]) + (v[2] + v[3]);
        float s23 = (v[4] + v[5]) + (v[6] + v[7]);
        float s45 = (v[8] + v[9]) + (v[10] + v[11]);
        float s67 = (v[12] + v[13]) + (v[14] + v[15]);
        float sm = (s01 + s23) + (s45 + s67);
        sm += __shfl_xor(sm, 16);
        sm += __shfl_xor(sm, 32);
        const float isv = 1.0f / sm;

        // PV (operand-swapped): O^T = V^T . P^T ; rho makes B-frag = e[0..7]/e[8..15]
        bf16x8 bp0, bp1;
        #pragma unroll
        for (int j = 0; j < 8; ++j) { bp0[j] = (bf16)v[j]; bp1[j] = (bf16)v[8 + j]; }
        const bf16* vb = VT + (32 * h + l16) * 72 + koff;
        f32x4 o0 = zero4, o1 = zero4;
        o0 = MFMA16(*(const bf16x8*)(vb),                bp0, o0);
        o0 = MFMA16(*(const bf16x8*)(vb + 32),           bp1, o0);
        o1 = MFMA16(*(const bf16x8*)(vb + 16 * 72),      bp0, o1);
        o1 = MFMA16(*(const bf16x8*)(vb + 16 * 72 + 32), bp1, o1);

        // proj (operand-swapped, fused per head): out^T += Wp(:, head h, permuted) . O_h^T
        bf16x8 bo;
        #pragma unroll
        for (int r = 0; r < 4; ++r) { bo[r] = (bf16)(o0[r] * isv); bo[4 + r] = (bf16)(o1[r] * isv); }
        #pragma unroll
        for (int t = 0; t < 6; ++t)
            dacc[t] = MFMA16(WP[(t * 3 + h) * 64], bo, dacc[t]);
    }

    // ---- store: out^T rows = channels (16t+4q+r consecutive -> dwordx4), col = my pixel ----
    if (pq < 49) {
        #pragma unroll
        for (int t = 0; t < 6; ++t) {
            const f32x4 pb = *(const f32x4*)(proj_b + 16 * t + 4 * quad);
            f32x4 ov;
            #pragma unroll
            for (int r = 0; r < 4; ++r) ov[r] = dacc[t][r] + pb[r];
            *(f32x4*)(out + gbase + 16 * t + 4 * quad) = ov;
        }
    }
}

extern "C" void kernel_launch(void* const* d_in, const int* in_sizes, int n_in,
                              void* d_out, int out_size, void* d_ws, size_t ws_size,
                              hipStream_t stream) {
    (void)in_sizes; (void)n_in; (void)out_size; (void)ws_size;
    prep<<<dim3(210), dim3(256), 0, stream>>>(
        (const float*)d_in[2], (const float*)d_in[4], (const float*)d_in[6],
        (const float*)d_in[8], (bf16*)d_ws);
    swin_msa_kernel<<<dim3(4096), dim3(256), 0, stream>>>(
        (const float*)d_in[0], (const float*)d_in[1], (const bf16*)d_ws,
        (const float*)d_in[3], (const float*)d_in[5], (const float*)d_in[7],
        (float*)d_out);
}

// Round 4
// 263.689 us; speedup vs baseline: 1.1808x; 1.1808x over previous
//
#include <hip/hip_runtime.h>

typedef __bf16 bf16;
typedef __attribute__((ext_vector_type(8))) __bf16 bf16x8;
typedef __attribute__((ext_vector_type(4))) __bf16 bf16x4;
typedef __attribute__((ext_vector_type(4))) float f32x4;

#define MFMA16(a, b, c) __builtin_amdgcn_mfma_f32_16x16x32_bf16(a, b, c, 0, 0, 0)

__device__ __forceinline__ int div7(int n) { return (n * 37) >> 8; }          // exact 0..63
__device__ __forceinline__ int relv(int n) { return n + 6 * div7(n); }        // 13*(n/7)+(n%7)

#define QSCALE 0.17677669529663687f   // 32^-0.5, folded into Q

// Streaming load of 8 consecutive fp32 (read-once data), round to bf16x8.
__device__ __forceinline__ bf16x8 LD8NT(const float* p) {
    f32x4 a = __builtin_nontemporal_load((const f32x4*)p);
    f32x4 b = __builtin_nontemporal_load((const f32x4*)(p + 4));
    bf16x8 r;
    r[0] = (bf16)a[0]; r[1] = (bf16)a[1]; r[2] = (bf16)a[2]; r[3] = (bf16)a[3];
    r[4] = (bf16)b[0]; r[5] = (bf16)b[1]; r[6] = (bf16)b[2]; r[7] = (bf16)b[3];
    return r;
}

// ---------------- prep: pack weights (bf16 MFMA B-frag order) + bake logit tables ---------
// ws layout:
//   bf16x8 frags [0,2304): Wq  [t=0..11][ks=0..2][lane]  (qkv_w)
//                [2304,3456): Wsk [t=0..5][ks=0..2][lane] (skip_w * QSCALE)
//                [3456,4608): Wpr [t=0..5][h=0..2][lane]  (proj_w, permuted quad layout)
//   f32 PB at byte 73728: [vh=12][quad=4][nt=4][q=64][r=4] logit offsets
//     (key = 8*quad + 32*(nt>>1) + 4*(nt&1) + r), vh = variant*3 + h,
//     variant = (wi==31)*2 + (wj==31); value = bias + (-100 mask) + (-20000 key-pad)
__global__ __launch_bounds__(256)
void prep(const float* __restrict__ qkv_w, const float* __restrict__ skip_w,
          const float* __restrict__ proj_w, const float* __restrict__ btab,
          bf16* __restrict__ ws)
{
    const int blk = blockIdx.x, tid = threadIdx.x;
    if (blk < 18) {
        const int j = blk * 256 + tid;
        bf16x8 v;
        if (j < 2304) {
            int t = j / 192, rem = j - t * 192;
            int ks = rem >> 6, lane = rem & 63, q = lane >> 4, l16 = lane & 15;
            const float* p = qkv_w + (16 * t + l16) * 96 + ks * 32 + q * 8;
            #pragma unroll
            for (int e = 0; e < 8; ++e) v[e] = (bf16)p[e];
        } else if (j < 3456) {
            int i = j - 2304;
            int t = i / 192, rem = i - t * 192;
            int ks = rem >> 6, lane = rem & 63, q = lane >> 4, l16 = lane & 15;
            const float* p = skip_w + (16 * t + l16) * 96 + ks * 32 + q * 8;
            #pragma unroll
            for (int e = 0; e < 8; ++e) v[e] = (bf16)(p[e] * QSCALE);
        } else {
            int i = j - 3456;
            int t = i / 192, rem = i - t * 192;
            int h = rem >> 6, lane = rem & 63, q = lane >> 4, l16 = lane & 15;
            const float* p = proj_w + (16 * t + l16) * 96 + 32 * h + 4 * q;
            #pragma unroll
            for (int r = 0; r < 4; ++r) { v[r] = (bf16)p[r]; v[4 + r] = (bf16)p[16 + r]; }
        }
        ((bf16x8*)ws)[j] = v;
    } else {
        const int idx = (blk - 18) * 256 + tid;          // 0..49151
        const int r  = idx & 3;
        const int q  = (idx >> 2) & 63;
        const int nt = (idx >> 8) & 3;
        const int qd = (idx >> 10) & 3;
        const int vh = idx >> 12;                        // variant*3 + h
        const int vr = vh / 3, h = vh - 3 * vr;
        const int ebit = vr >> 1, wbit = vr & 1;         // (wi==31), (wj==31)
        const int k = 8 * qd + 32 * (nt >> 1) + 4 * (nt & 1) + r;
        const int qc = (q < 49) ? q : 48;
        float val;
        if (k >= 49) {
            val = -20000.f;
        } else {
            val = btab[(relv(qc) + relv(48 - k)) * 3 + h];
            int rq = div7(qc), cq = qc - 7 * rq;
            int rk = div7(k),  ck = k - 7 * rk;
            int gq = (ebit ? (rq < 4 ? 3 : 6) : 0) + (wbit ? (cq < 4 ? 1 : 2) : 0);
            int gk = (ebit ? (rk < 4 ? 3 : 6) : 0) + (wbit ? (ck < 4 ? 1 : 2) : 0);
            if (gq != gk) val -= 100.f;
        }
        ((float*)(ws + 36864))[idx] = val;
    }
}

// ---------------- main: one block = one 7x7 window, 256 threads = 4 waves ----------------
__global__ __launch_bounds__(256, 4)
void swin_msa_kernel(const float* __restrict__ x_in,   const float* __restrict__ sx_in,
                     const bf16*  __restrict__ wpk,    const float* __restrict__ qkv_b,
                     const float* __restrict__ skip_b, const float* __restrict__ proj_b,
                     float* __restrict__ out)
{
    // LDS: X 64x104 (staged input, later overlaid by Qb), Kb 64x104 (rho-permuted rows),
    //      VT 96x72 = 40448 B -> 4 blocks/CU
    __shared__ __align__(16) unsigned short smem[20224];
    bf16* X  = (bf16*)smem;       // 64 x 104 staged x (bf16); Qb overlays after barrier 2
    bf16* Qb = X;
    bf16* Kb = X + 6656;          // 64 x 104
    bf16* VT = Kb + 6656;         // 96 x 72  (V transposed: [channel][pixel])

    const int tid  = threadIdx.x;
    const int wv   = tid >> 6;
    const int lane = tid & 63;
    const int quad = lane >> 4;
    const int l16  = lane & 15;

    const int win  = blockIdx.x;
    const int bimg = win >> 10;
    const int wrem = win & 1023;
    const int wi   = wrem >> 5;
    const int wj   = wrem & 31;

    const f32x4 zero4 = {0.f, 0.f, 0.f, 0.f};
    const int koff = quad * 8;

    // packed weight fragment streams for THIS lane (wave reads dense 1 KB per instr)
    const bf16x8* WQ = (const bf16x8*)wpk + lane;          // + (t*3+ks)*64
    const bf16x8* WS = (const bf16x8*)wpk + 2304 + lane;   // + (t*3+ks)*64
    const bf16x8* WP = (const bf16x8*)wpk + 3456 + lane;   // + (t*3+h)*64

    // my pixel: p = 16*wv + l16
    const int pq  = 16 * wv + l16;
    const int pqc = (pq < 49) ? pq : 48;
    int pr = div7(pqc), pc = pqc - 7 * pr;
    int h0 = wi * 7 + pr + 3; if (h0 >= 224) h0 -= 224;     // roll(-3) gather
    int w0 = wj * 7 + pc + 3; if (w0 >= 224) w0 -= 224;
    const int gbase = ((bimg * 224 + h0) * 224 + w0) * 96;

    // hoist B2's sx loads to the very top: latency hides under gather+B1
    bf16x8 asx[3];
    #pragma unroll
    for (int ks = 0; ks < 3; ++ks) asx[ks] = LD8NT(sx_in + gbase + ks * 32 + koff);

    // ---- stage A: cooperative dense gather of X -> LDS (bf16), 4 threads/pixel ----
    {
        const int p   = tid >> 2;
        const int seg = tid & 3;
        const int pcl = (p < 49) ? p : 48;
        int rr = div7(pcl), cc = pcl - 7 * rr;
        int gh = wi * 7 + rr + 3; if (gh >= 224) gh -= 224;
        int gw = wj * 7 + cc + 3; if (gw >= 224) gw -= 224;
        const float* src = x_in + ((bimg * 224 + gh) * 224 + gw) * 96 + seg * 24;
        bf16* dst = X + p * 104 + seg * 24;
        f32x4 a0 = __builtin_nontemporal_load((const f32x4*)src);
        f32x4 a1 = __builtin_nontemporal_load((const f32x4*)(src + 4));
        f32x4 a2 = __builtin_nontemporal_load((const f32x4*)(src + 8));
        f32x4 a3 = __builtin_nontemporal_load((const f32x4*)(src + 12));
        f32x4 a4 = __builtin_nontemporal_load((const f32x4*)(src + 16));
        f32x4 a5 = __builtin_nontemporal_load((const f32x4*)(src + 20));
        bf16x8 w0, w1, w2;
        #pragma unroll
        for (int e = 0; e < 4; ++e) {
            w0[e] = (bf16)a0[e]; w0[4 + e] = (bf16)a1[e];
            w1[e] = (bf16)a2[e]; w1[4 + e] = (bf16)a3[e];
            w2[e] = (bf16)a4[e]; w2[4 + e] = (bf16)a5[e];
        }
        *(bf16x8*)(dst)      = w0;
        *(bf16x8*)(dst + 8)  = w1;
        *(bf16x8*)(dst + 16) = w2;
    }
    __syncthreads();   // barrier 1: X staged

    // ---- stage B1 (N-split): KV = X @ qkv_w^T + b; wave wv owns t = 3wv..3wv+2 ----
    {
        f32x4 acc[4][3];
        #pragma unroll
        for (int m = 0; m < 4; ++m)
            #pragma unroll
            for (int j = 0; j < 3; ++j) acc[m][j] = zero4;
        const int tb = 3 * wv;
        #pragma unroll
        for (int ks = 0; ks < 3; ++ks) {
            bf16x8 a[4];
            #pragma unroll
            for (int m = 0; m < 4; ++m)
                a[m] = *(const bf16x8*)(X + (16 * m + l16) * 104 + ks * 32 + koff);
            #pragma unroll
            for (int j = 0; j < 3; ++j) {
                bf16x8 b = WQ[((tb + j) * 3 + ks) * 64];
                #pragma unroll
                for (int m = 0; m < 4; ++m) acc[m][j] = MFMA16(a[m], b, acc[m][j]);
            }
        }
        if (wv < 2) {
            // K columns 16*tb .. 16*tb+47, rows rho-permuted by key = 16m+4quad+r
            #pragma unroll
            for (int j = 0; j < 3; ++j) {
                const int col = 16 * (tb + j) + l16;
                const float bias = qkv_b[col];
                #pragma unroll
                for (int m = 0; m < 4; ++m) {
                    const int rho = 32 * (m >> 1) + 16 * (quad & 1) + 8 * (m & 1) + 4 * (quad >> 1);
                    #pragma unroll
                    for (int r = 0; r < 4; ++r)
                        Kb[(rho + r) * 104 + col] = (bf16)(acc[m][j][r] + bias);
                }
            }
        } else {
            // V channels 16*(tb-6) .. +47, stored transposed [ch][pixel]
            #pragma unroll
            for (int j = 0; j < 3; ++j) {
                const int ch = 16 * (tb + j - 6) + l16;
                const float bias = qkv_b[16 * (tb + j) + l16];
                #pragma unroll
                for (int m = 0; m < 4; ++m) {
                    bf16x4 vv;
                    #pragma unroll
                    for (int r = 0; r < 4; ++r) vv[r] = (bf16)(acc[m][j][r] + bias);
                    *(bf16x4*)(VT + ch * 72 + 16 * m + 4 * quad) = vv;
                }
            }
        }
    }
    __syncthreads();   // barrier 2: X dead; Qb may overlay

    // ---- stage B2 (M-split): Q = SX @ (skip_w*scale)^T + b*scale ----
    {
        f32x4 qa[6];
        #pragma unroll
        for (int t = 0; t < 6; ++t) qa[t] = zero4;
        #pragma unroll
        for (int ks = 0; ks < 3; ++ks)
            #pragma unroll
            for (int t = 0; t < 6; ++t)
                qa[t] = MFMA16(asx[ks], WS[(t * 3 + ks) * 64], qa[t]);
        const int row = 16 * wv + 4 * quad;
        #pragma unroll
        for (int t = 0; t < 6; ++t) {
            const float bias = skip_b[16 * t + l16] * QSCALE;
            #pragma unroll
            for (int r = 0; r < 4; ++r)
                Qb[(row + r) * 104 + 16 * t + l16] = (bf16)(qa[t][r] + bias);
        }
    }
    __syncthreads();   // barrier 3: Kb/Qb/VT visible, read-only hereafter

    // ---- stage C: attention + proj, fully in registers ----
    const int variant = ((wi == 31) ? 2 : 0) + ((wj == 31) ? 1 : 0);
    const f32x4* PB4 = (const f32x4*)((const float*)(wpk + 36864));
    // f32x4 index: ((vh*4 + quad)*4 + nt)*64 + pq

    f32x4 dacc[6];
    #pragma unroll
    for (int t = 0; t < 6; ++t) dacc[t] = zero4;

    #pragma unroll
    for (int h = 0; h < 3; ++h) {
        const int pbase = (((variant * 3 + h) * 4 + quad) * 4) * 64 + pq;
        // S^T = K_perm . Q^T with C = baked logit offsets
        const bf16x8 bq = *(const bf16x8*)(Qb + (16 * wv + l16) * 104 + 32 * h + koff);
        f32x4 s[4];
        #pragma unroll
        for (int nt = 0; nt < 4; ++nt) {
            bf16x8 ak = *(const bf16x8*)(Kb + (16 * nt + l16) * 104 + 32 * h + koff);
            s[nt] = MFMA16(ak, bq, PB4[pbase + nt * 64]);
        }
        // max-free softmax: logits are O(1); masks underflow exp to 0 exactly
        float v[16];
        #pragma unroll
        for (int nt = 0; nt < 4; ++nt)
            #pragma unroll
            for (int r = 0; r < 4; ++r) v[nt * 4 + r] = __expf(s[nt][r]);
        float s01 = (v[0] + v[1]) + (v[2] + v[3]);
        float s23 = (v[4] + v[5]) + (v[6] + v[7]);
        float s45 = (v[8] + v[9]) + (v[10] + v[11]);
        float s67 = (v[12] + v[13]) + (v[14] + v[15]);
        float sm = (s01 + s23) + (s45 + s67);
        sm += __shfl_xor(sm, 16);
        sm += __shfl_xor(sm, 32);
        const float isv = 1.0f / sm;

        // PV (operand-swapped): O^T = V^T . P^T ; rho makes B-frag = e[0..7]/e[8..15]
        bf16x8 bp0, bp1;
        #pragma unroll
        for (int j = 0; j < 8; ++j) { bp0[j] = (bf16)v[j]; bp1[j] = (bf16)v[8 + j]; }
        const bf16* vb = VT + (32 * h + l16) * 72 + koff;
        f32x4 o0 = zero4, o1 = zero4;
        o0 = MFMA16(*(const bf16x8*)(vb),                bp0, o0);
        o0 = MFMA16(*(const bf16x8*)(vb + 32),           bp1, o0);
        o1 = MFMA16(*(const bf16x8*)(vb + 16 * 72),      bp0, o1);
        o1 = MFMA16(*(const bf16x8*)(vb + 16 * 72 + 32), bp1, o1);

        // proj (operand-swapped, fused per head): out^T += Wp(:, head h, permuted) . O_h^T
        bf16x8 bo;
        #pragma unroll
        for (int r = 0; r < 4; ++r) { bo[r] = (bf16)(o0[r] * isv); bo[4 + r] = (bf16)(o1[r] * isv); }
        #pragma unroll
        for (int t = 0; t < 6; ++t)
            dacc[t] = MFMA16(WP[(t * 3 + h) * 64], bo, dacc[t]);
    }

    // ---- store: out^T rows = channels (16t+4q+r consecutive -> dwordx4), col = my pixel ----
    if (pq < 49) {
        #pragma unroll
        for (int t = 0; t < 6; ++t) {
            const f32x4 pb = *(const f32x4*)(proj_b + 16 * t + 4 * quad);
            f32x4 ov;
            #pragma unroll
            for (int r = 0; r < 4; ++r) ov[r] = dacc[t][r] + pb[r];
            *(f32x4*)(out + gbase + 16 * t + 4 * quad) = ov;
        }
    }
}

extern "C" void kernel_launch(void* const* d_in, const int* in_sizes, int n_in,
                              void* d_out, int out_size, void* d_ws, size_t ws_size,
                              hipStream_t stream) {
    (void)in_sizes; (void)n_in; (void)out_size; (void)ws_size;
    prep<<<dim3(210), dim3(256), 0, stream>>>(
        (const float*)d_in[2], (const float*)d_in[4], (const float*)d_in[6],
        (const float*)d_in[8], (bf16*)d_ws);
    swin_msa_kernel<<<dim3(4096), dim3(256), 0, stream>>>(
        (const float*)d_in[0], (const float*)d_in[1], (const bf16*)d_ws,
        (const float*)d_in[3], (const float*)d_in[5], (const float*)d_in[7],
        (float*)d_out);
}